// Round 1
// baseline (3310.844 us; speedup 1.0000x reference)
//
#include <hip/hip_runtime.h>
#include <hip/hip_bf16.h>
#include <cstdint>
#include <cstddef>

#define TPB 256
#define KT 128          // k rows per block
#define BT 128          // batch columns (all of B)
#define DC 32           // depth chunk staged in LDS
#define SPLITS 32       // depth splits for grid parallelism
#define LDSP (DC + 4)   // padded LDS row stride (36 floats = 144 B, 16B-aligned rows)

// ---------------- kernel 1: L = log(logits) ----------------
__global__ void log_kernel(const float* __restrict__ x, float* __restrict__ y, int n) {
    int i = blockIdx.x * blockDim.x + threadIdx.x;
    int i4 = i * 4;
    if (i4 + 3 < n) {
        float4 v = *reinterpret_cast<const float4*>(x + i4);
        float4 r;
        r.x = logf(v.x); r.y = logf(v.y); r.z = logf(v.z); r.w = logf(v.w);
        *reinterpret_cast<float4*>(y + i4) = r;
    } else {
        for (int q = i4; q < n; ++q) y[q] = logf(x[q]);
    }
}

// ---------------- kernel 2: cross[k][b] += sum_d A[k,d]*L[b,d]; self[k] += sum_d A*log(A) ----------------
__launch_bounds__(TPB, 4)
__global__ void gemm_kernel(const float* __restrict__ A,      // [K][D] queue_anchor
                            const float* __restrict__ L,      // [B][D] log(logits)
                            float* __restrict__ cross,        // [K][B] partial sums (atomic)
                            float* __restrict__ selfsum,      // [K]    partial sums (atomic)
                            int D, int splitLen)
{
    __shared__ float Al[KT][LDSP];
    __shared__ float Ll[BT][LDSP];

    const int tid  = threadIdx.x;
    const int k0   = blockIdx.x * KT;
    const int d0s  = blockIdx.y * splitLen;
    const int dEnd = min(d0s + splitLen, D);

    const int kg  = tid >> 4;        // 0..15 : k sub-row group
    const int bg  = tid & 15;        // 0..15 : b sub-col group
    const int srow = tid >> 3;       // 0..31 : staging row
    const int sd4  = (tid & 7) * 4;  // staging d offset (float4)

    float acc[8][8];
#pragma unroll
    for (int i = 0; i < 8; ++i)
#pragma unroll
        for (int j = 0; j < 8; ++j) acc[i][j] = 0.f;

    float selfacc[4] = {0.f, 0.f, 0.f, 0.f};

    for (int d0 = d0s; d0 < dEnd; d0 += DC) {
        if (d0 + DC <= dEnd) {
            // fast path: full chunk, float4 staging
#pragma unroll
            for (int r = 0; r < 4; ++r) {
                const int row = srow + 32 * r;
                float4 va = *reinterpret_cast<const float4*>(&A[(size_t)(k0 + row) * D + d0 + sd4]);
                *reinterpret_cast<float4*>(&Al[row][sd4]) = va;
                selfacc[r] += va.x * logf(va.x) + va.y * logf(va.y)
                            + va.z * logf(va.z) + va.w * logf(va.w);
                float4 vl = *reinterpret_cast<const float4*>(&L[(size_t)row * D + d0 + sd4]);
                *reinterpret_cast<float4*>(&Ll[row][sd4]) = vl;
            }
        } else {
            // tail chunk: scalar with zero-fill
            for (int r = 0; r < 4; ++r) {
                const int row = srow + 32 * r;
                for (int q = 0; q < 4; ++q) {
                    int d = d0 + sd4 + q;
                    float a = 0.f, l = 0.f;
                    if (d < dEnd) {
                        a = A[(size_t)(k0 + row) * D + d];
                        l = L[(size_t)row * D + d];
                        selfacc[r] += a * logf(a);
                    }
                    Al[row][sd4 + q] = a;
                    Ll[row][sd4 + q] = l;
                }
            }
        }
        __syncthreads();

#pragma unroll
        for (int dd = 0; dd < DC; dd += 4) {
            float4 av[8];
#pragma unroll
            for (int i = 0; i < 8; ++i)
                av[i] = *reinterpret_cast<const float4*>(&Al[kg + 16 * i][dd]);
#pragma unroll
            for (int j = 0; j < 8; ++j) {
                float4 lv = *reinterpret_cast<const float4*>(&Ll[bg + 16 * j][dd]);
#pragma unroll
                for (int i = 0; i < 8; ++i) {
                    acc[i][j] = fmaf(av[i].x, lv.x, acc[i][j]);
                    acc[i][j] = fmaf(av[i].y, lv.y, acc[i][j]);
                    acc[i][j] = fmaf(av[i].z, lv.z, acc[i][j]);
                    acc[i][j] = fmaf(av[i].w, lv.w, acc[i][j]);
                }
            }
        }
        __syncthreads();
    }

    // write partial cross sums
#pragma unroll
    for (int i = 0; i < 8; ++i) {
        const int k = k0 + kg + 16 * i;
#pragma unroll
        for (int j = 0; j < 8; ++j)
            atomicAdd(&cross[(size_t)k * BT + bg + 16 * j], acc[i][j]);
    }
    // reduce self-term across the 8 staging threads that share a row
#pragma unroll
    for (int r = 0; r < 4; ++r) {
        float v = selfacc[r];
        v += __shfl_xor(v, 1);
        v += __shfl_xor(v, 2);
        v += __shfl_xor(v, 4);
        if ((tid & 7) == 0) atomicAdd(&selfsum[k0 + srow + 32 * r], v);
    }
}

// ---------------- kernel 3: per-row top-8, softmax, label scatter ----------------
__global__ void topk_kernel(const float* __restrict__ cross, const float* __restrict__ selfsum,
                            const int* __restrict__ labels, float* __restrict__ out,
                            int K, float invDT)
{
    const int b = blockIdx.x;    // 0..B-1
    const int t = threadIdx.x;   // 0..63

    float v[8]; int idx[8];
#pragma unroll
    for (int r = 0; r < 8; ++r) { v[r] = -1e30f; idx[r] = -1; }

    for (int k = t; k < K; k += 64) {
        float s = (cross[(size_t)k * BT + b] - selfsum[k]) * invDT;  // scaled = (cross-self)/(D*T)
        if (s > v[7]) {
            int pos = 7;
#pragma unroll
            for (int r = 6; r >= 0; --r) {
                if (s > v[r]) { v[r + 1] = v[r]; idx[r + 1] = idx[r]; pos = r; }
            }
            v[pos] = s; idx[pos] = k;
        }
    }

    __shared__ float sv[64 * 8];
    __shared__ int   si[64 * 8];
#pragma unroll
    for (int r = 0; r < 8; ++r) { sv[t * 8 + r] = v[r]; si[t * 8 + r] = idx[r]; }
    __syncthreads();

    if (t == 0) {
        float fv[8]; int fi[8];
        for (int r = 0; r < 8; ++r) { fv[r] = -1e30f; fi[r] = -1; }
        for (int c = 0; c < 64 * 8; ++c) {
            float s = sv[c];
            if (s > fv[7]) {
                int ii = si[c];
                int pos = 7;
                for (int r = 6; r >= 0; --r) {
                    if (s > fv[r]) { fv[r + 1] = fv[r]; fi[r + 1] = fi[r]; pos = r; }
                }
                fv[pos] = s; fi[pos] = ii;
            }
        }
        float m = fv[0];
        float e[8], sum = 0.f;
        for (int r = 0; r < 8; ++r) { e[r] = expf(fv[r] - m); sum += e[r]; }
        float o0 = 0.f, o1 = 0.f;
        for (int r = 0; r < 8; ++r) {
            float w = e[r] / sum;
            if (labels[fi[r]] == 1) o1 += w; else o0 += w;
        }
        out[b * 2 + 0] = o0;
        out[b * 2 + 1] = o1;
    }
}

extern "C" void kernel_launch(void* const* d_in, const int* in_sizes, int n_in,
                              void* d_out, int out_size, void* d_ws, size_t ws_size,
                              hipStream_t stream)
{
    const float* logits = (const float*)d_in[0];   // [B][D]
    const float* anchor = (const float*)d_in[1];   // [K][D]
    const int*   labels = (const int*)d_in[2];     // [K]

    const int K = in_sizes[2];
    const int D = in_sizes[1] / K;
    const int B = in_sizes[0] / D;   // 128

    // workspace layout: L (B*D f32) | cross (K*B f32) | selfsum (K f32)
    float* Lbuf    = (float*)d_ws;
    float* cross   = (float*)((char*)d_ws + (size_t)B * D * sizeof(float));
    float* selfsum = cross + (size_t)K * B;

    hipMemsetAsync(cross, 0, ((size_t)K * B + K) * sizeof(float), stream);

    const int n = B * D;
    const int nthreads = (n + 3) / 4;
    log_kernel<<<(nthreads + TPB - 1) / TPB, TPB, 0, stream>>>(logits, Lbuf, n);

    const int splitLen = (D + SPLITS - 1) / SPLITS;
    dim3 grid(K / KT, SPLITS);
    gemm_kernel<<<grid, TPB, 0, stream>>>(anchor, Lbuf, cross, selfsum, D, splitLen);

    const float invDT = 1.0f / ((float)D * 0.05f);
    topk_kernel<<<B, 64, 0, stream>>>(cross, selfsum, labels, (float*)d_out, K, invDT);
}